// Round 7
// baseline (3960.101 us; speedup 1.0000x reference)
//
#include <hip/hip_runtime.h>
#include <cmath>
#include <stdint.h>

#define BB 32
#define TT 24
#define NN 1024
#define FF 2
#define UU 16
#define HH 32
#define TFN 31

typedef __attribute__((ext_vector_type(8))) short bf16x8;
typedef __attribute__((ext_vector_type(4))) float f32x4;
typedef unsigned short u16;
typedef unsigned int   u32;

#define MFMA16x16 __builtin_amdgcn_mfma_f32_16x16x32_bf16

// ---- static device buffers (fully rewritten every call) ----
__device__ __align__(16) u16 g_Ab [(size_t)BB*NN*NN];  // bf16 A, row-major [b][i][k]
__device__ __align__(16) u16 g_ru [(size_t)BB*64*NN];  // bf16 [b][j][n]: j<32 ru2(t) / j>=32 ru1(t+1)
__device__ __align__(16) u16 g_cin[(size_t)BB*32*NN];  // bf16 [b][j][n]: j<16 c_in2(t) / j>=16 c_in1(t+1)
__device__ float g_h1[BB*NN*UU];
__device__ float g_h2[BB*NN*UU];
__device__ float g_u1[BB*NN*UU];
__device__ float g_u2[BB*NN*UU];
__device__ float g_c2[BB*FF];

__device__ __forceinline__ float sigmf(float x) { return 1.0f/(1.0f+expf(-x)); }
__device__ __forceinline__ u16 f2bf(float f) {      // RNE fp32 -> bf16
  u32 u = __float_as_uint(f);
  return (u16)((u + 0x7fffu + ((u >> 16) & 1u)) >> 16);
}

// ---------------- convert A fp32 -> bf16 ----------------
__global__ __launch_bounds__(256)
void k_convert(const float* __restrict__ A) {
  size_t idx = ((size_t)blockIdx.x*256 + threadIdx.x)*8;
  float4 v0 = *(const float4*)(A + idx);
  float4 v1 = *(const float4*)(A + idx + 4);
  u32 p0 = (u32)f2bf(v0.x) | ((u32)f2bf(v0.y) << 16);
  u32 p1 = (u32)f2bf(v0.z) | ((u32)f2bf(v0.w) << 16);
  u32 p2 = (u32)f2bf(v1.x) | ((u32)f2bf(v1.y) << 16);
  u32 p3 = (u32)f2bf(v1.z) | ((u32)f2bf(v1.w) << 16);
  *(uint4*)&g_Ab[idx] = make_uint4(p0, p1, p2, p3);
}

// ---------------- init: zero h1/h2, ru_in1(0) into g_ru[j=0..31] ----------------
__global__ __launch_bounds__(256)
void k_init(const float* __restrict__ recent,
            const float* __restrict__ rW1, const float* __restrict__ uW1) {
  int idx = blockIdx.x*256 + threadIdx.x;
  if (idx >= BB*NN) return;
  int b = idx >> 10, n = idx & (NN-1);
  float x0 = recent[((size_t)(b*TT)*NN + n)*FF + 0];
  float x1 = recent[((size_t)(b*TT)*NN + n)*FF + 1];
#pragma unroll
  for (int j=0;j<16;j++) {
    g_ru[((size_t)(b*64+j))*NN + n]    = f2bf(x0*rW1[j*18+0] + x1*rW1[j*18+1]);
    g_ru[((size_t)(b*64+16+j))*NN + n] = f2bf(x0*uW1[j*18+0] + x1*uW1[j*18+1]);
  }
  float* h1 = g_h1 + (size_t)idx*16;
  float* h2 = g_h2 + (size_t)idx*16;
#pragma unroll
  for (int j=0;j<16;j++) { h1[j]=0.f; h2[j]=0.f; }
}

// ---------------- LSTM + ff + const2 (tiny) ----------------
__global__ __launch_bounds__(128)
void k_lstm(const float* __restrict__ trend, const float* __restrict__ tfeat,
            const float* __restrict__ Wih0, const float* __restrict__ Whh0,
            const float* __restrict__ bih0, const float* __restrict__ bhh0,
            const float* __restrict__ Wih1, const float* __restrict__ Whh1,
            const float* __restrict__ bih1, const float* __restrict__ bhh1,
            const float* __restrict__ ffW, const float* __restrict__ ffb,
            const float* __restrict__ gcnW) {
  __shared__ float h[HH], c[HH], g[4*HH], hs0[TT][HH], tr[HH], fe[HH];
  int b = blockIdx.x, tid = threadIdx.x;
  if (tid < HH) { h[tid]=0.f; c[tid]=0.f; }
  __syncthreads();
  for (int t=0;t<TT;t++) {
    float x0 = trend[(b*TT+t)*FF+0], x1 = trend[(b*TT+t)*FF+1];
    float gv = bih0[tid] + bhh0[tid] + x0*Wih0[tid*FF+0] + x1*Wih0[tid*FF+1];
#pragma unroll
    for (int k=0;k<HH;k++) gv += h[k]*Whh0[tid*HH+k];
    g[tid] = gv;
    __syncthreads();
    if (tid < HH) {
      float ii = sigmf(g[tid]), ff = sigmf(g[HH+tid]);
      float gg = tanhf(g[2*HH+tid]), oo = sigmf(g[3*HH+tid]);
      float cn = ff*c[tid] + ii*gg;
      c[tid] = cn;
      float hn = oo*tanhf(cn);
      h[tid] = hn;
      hs0[t][tid] = hn;
    }
    __syncthreads();
  }
  if (tid < HH) { h[tid]=0.f; c[tid]=0.f; }
  __syncthreads();
  for (int t=0;t<TT;t++) {
    float gv = bih1[tid] + bhh1[tid];
#pragma unroll
    for (int k=0;k<HH;k++) gv += hs0[t][k]*Wih1[tid*HH+k];
#pragma unroll
    for (int k=0;k<HH;k++) gv += h[k]*Whh1[tid*HH+k];
    g[tid] = gv;
    __syncthreads();
    if (tid < HH) {
      float ii = sigmf(g[tid]), ff = sigmf(g[HH+tid]);
      float gg = tanhf(g[2*HH+tid]), oo = sigmf(g[3*HH+tid]);
      float cn = ff*c[tid] + ii*gg;
      c[tid] = cn;
      h[tid] = oo*tanhf(cn);
    }
    __syncthreads();
  }
  if (tid < HH) {
    tr[tid] = h[tid];
    float fv = ffb[tid];
#pragma unroll
    for (int j=0;j<TFN;j++) fv += tfeat[b*TFN+j]*ffW[tid*TFN+j];
    fe[tid] = fmaxf(fv, 0.f);
  }
  __syncthreads();
  if (tid < FF) {
    float s = 0.f;
#pragma unroll
    for (int j=0;j<HH;j++) s += tr[j]*gcnW[tid*80+16+j];
#pragma unroll
    for (int j=0;j<HH;j++) s += fe[j]*gcnW[tid*80+48+j];
    g_c2[b*FF+tid] = s;
  }
}

// ============ KA: width-64 pass P = A @ [ru2(t) | ru1(t+1)] ============
// 32-row tile, 256 thr, ping-pong LDS, 1 barrier/chunk; grid (32, BB).
// Epilogue: r2,u2(t)->g_u2, c_in2(t); r1,u1(t+1)->g_u1, c_in1(t+1).
__global__ __launch_bounds__(256)
void k_ka(const float* __restrict__ xnext,
          const float* __restrict__ b2r, const float* __restrict__ b2u,
          const float* __restrict__ b1r, const float* __restrict__ b1u,
          const float* __restrict__ cW2, const float* __restrict__ cW1) {
  __shared__ __align__(16) char SM[52224];
  u16 (*As)[32][136] = (u16 (*)[32][136])SM;            // 2 x 8704
  u16 (*Ys)[64][136] = (u16 (*)[64][136])(SM + 17408);  // 2 x 17408
  float (*P)[68]   = (float (*)[68])SM;                 // 8704 (aliases As, used post-K)
  float (*H1s)[17] = (float (*)[17])(SM + 8704);
  float (*RH2)[17] = (float (*)[17])(SM + 10880);
  float (*RH1)[17] = (float (*)[17])(SM + 13056);
  const int b = blockIdx.y, i0 = blockIdx.x*32, tid = threadIdx.x;
  const int w = tid>>6, lane = tid&63, m = lane&15, quad = lane>>4;
  const int rh = w&1, ch = w>>1;
  const int ar = tid>>3, ac = tid&7;     // A: 32 rows, 2 x uint4/thread
  const int yr = tid>>2, yc = tid&3;     // Y: 64 rows, 4 x uint4/thread
  const u16* Ag = g_Ab + ((size_t)(b*NN+i0))*NN;
  const u16* Yg = g_ru + (size_t)b*64*NN;
  uint4 apf[2], ypf[4];
#pragma unroll
  for (int q=0;q<2;q++) apf[q] = *(const uint4*)&Ag[(size_t)ar*NN + ac*8 + q*64];
#pragma unroll
  for (int q=0;q<4;q++) ypf[q] = *(const uint4*)&Yg[(size_t)yr*NN + yc*8 + q*32];
#pragma unroll
  for (int q=0;q<2;q++) *(uint4*)&As[0][ar][ac*8+q*64] = apf[q];
#pragma unroll
  for (int q=0;q<4;q++) *(uint4*)&Ys[0][yr][yc*8+q*32] = ypf[q];
  f32x4 acc0={0,0,0,0}, acc1={0,0,0,0};
#pragma unroll
  for (int c=0;c<8;c++) {
    if (c<7) {
      const int k0 = (c+1)*128;
#pragma unroll
      for (int q=0;q<2;q++) apf[q] = *(const uint4*)&Ag[(size_t)ar*NN + k0 + ac*8 + q*64];
#pragma unroll
      for (int q=0;q<4;q++) ypf[q] = *(const uint4*)&Yg[(size_t)yr*NN + k0 + yc*8 + q*32];
    }
    __syncthreads();
    const int cb = c&1;
#pragma unroll
    for (int s=0;s<4;s++) {
      bf16x8 af  = *(const bf16x8*)&As[cb][rh*16+m][s*32+quad*8];
      bf16x8 bb0 = *(const bf16x8*)&Ys[cb][ch*32+m][s*32+quad*8];
      bf16x8 bb1 = *(const bf16x8*)&Ys[cb][ch*32+16+m][s*32+quad*8];
      acc0 = MFMA16x16(af, bb0, acc0, 0, 0, 0);
      acc1 = MFMA16x16(af, bb1, acc1, 0, 0, 0);
    }
    if (c<7) {
      const int nb = (c+1)&1;
#pragma unroll
      for (int q=0;q<2;q++) *(uint4*)&As[nb][ar][ac*8+q*64] = apf[q];
#pragma unroll
      for (int q=0;q<4;q++) *(uint4*)&Ys[nb][yr][yc*8+q*32] = ypf[q];
    }
  }
  __syncthreads();   // all MFMA LDS reads done before P aliases As
#pragma unroll
  for (int r=0;r<4;r++) {
    P[rh*16+quad*4+r][ch*32+m]    = acc0[r];
    P[rh*16+quad*4+r][ch*32+16+m] = acc1[r];
  }
  __syncthreads();
  const int row = tid>>3, jr = tid&7, n = i0+row, bn = b*NN+n;
#pragma unroll
  for (int q=0;q<2;q++) {
    int j = jr*2+q;
    float h1v = g_h1[(size_t)bn*16 + j];
    float h2v = g_h2[(size_t)bn*16 + j];
    float r2 = sigmf(P[row][j]    + b2r[j]);
    float u2 = sigmf(P[row][16+j] + b2u[j]);
    g_u2[(size_t)bn*16+j] = u2;
    RH2[row][j] = r2*h2v;
    H1s[row][j] = h1v;
    float r1 = sigmf(P[row][32+j] + b1r[j]);
    float u1 = sigmf(P[row][48+j] + b1u[j]);
    g_u1[(size_t)bn*16+j] = u1;
    RH1[row][j] = r1*h1v;
  }
  __syncthreads();
  {
    const float* xr = xnext + ((size_t)b*TT*NN + n)*FF;
    float x0 = xr[0], x1 = xr[1];
#pragma unroll
    for (int q=0;q<2;q++) {
      int j = jr*2+q;
      float s2 = 0.f;
#pragma unroll
      for (int f=0;f<16;f++) s2 = fmaf(H1s[row][f], cW2[j*32+f], s2);
#pragma unroll
      for (int f=0;f<16;f++) s2 = fmaf(RH2[row][f], cW2[j*32+16+f], s2);
      g_cin[((size_t)(b*32+j))*NN + n] = f2bf(s2);
      float s1 = fmaf(x0, cW1[j*18+0], x1*cW1[j*18+1]);
#pragma unroll
      for (int f=0;f<16;f++) s1 = fmaf(RH1[row][f], cW1[j*18+2+f], s1);
      g_cin[((size_t)(b*32+16+j))*NN + n] = f2bf(s1);
    }
  }
}

// ============ width-32 pass ============
// MODE 0 = P1_FIRST (A@ru1(0): r1,u1 -> g_u1, c_in1(0))
// MODE 1 = KB       (A@[c2(t)|c1(t+1)]: h2,h1 update; ru2(t+1)+ru1(t+2))
// MODE 2 = KB_TAIL  (t=22: no ru1 output)
// MODE 3 = P3_LAST  (A@ru2(23): r2,u2 -> g_u2, c_in2(23))
template<int MODE>
__global__ __launch_bounds__(256)
void k_w32(const float* __restrict__ xp,
           const float* __restrict__ ba, const float* __restrict__ bb,
           const float* __restrict__ cW,
           const float* __restrict__ w1r, const float* __restrict__ w1u,
           const float* __restrict__ w2r, const float* __restrict__ w2u) {
  __shared__ __align__(16) char SM[34816];
  u16 (*As)[32][136] = (u16 (*)[32][136])SM;
  u16 (*Ys)[32][136] = (u16 (*)[32][136])(SM + 17408);
  float (*P)[36]  = (float (*)[36])SM;                 // 4608, aliases As
  float (*E1)[17] = (float (*)[17])(SM + 4608);
  float (*E2)[17] = (float (*)[17])(SM + 6784);
  const int b = blockIdx.y, i0 = blockIdx.x*32, tid = threadIdx.x;
  const int w = tid>>6, lane = tid&63, m = lane&15, quad = lane>>4;
  const int rh = w&1, ch = w>>1;
  const int ar = tid>>3, ac = tid&7;
  const u16* Ag = g_Ab + ((size_t)(b*NN+i0))*NN;
  const u16* Yg = (MODE==1||MODE==2) ? (g_cin + (size_t)b*32*NN) : (g_ru + (size_t)b*64*NN);
  uint4 apf[2], ypf[2];
#pragma unroll
  for (int q=0;q<2;q++) apf[q] = *(const uint4*)&Ag[(size_t)ar*NN + ac*8 + q*64];
#pragma unroll
  for (int q=0;q<2;q++) ypf[q] = *(const uint4*)&Yg[(size_t)ar*NN + ac*8 + q*64];
#pragma unroll
  for (int q=0;q<2;q++) *(uint4*)&As[0][ar][ac*8+q*64] = apf[q];
#pragma unroll
  for (int q=0;q<2;q++) *(uint4*)&Ys[0][ar][ac*8+q*64] = ypf[q];
  f32x4 acc0={0,0,0,0};
#pragma unroll
  for (int c=0;c<8;c++) {
    if (c<7) {
      const int k0 = (c+1)*128;
#pragma unroll
      for (int q=0;q<2;q++) apf[q] = *(const uint4*)&Ag[(size_t)ar*NN + k0 + ac*8 + q*64];
#pragma unroll
      for (int q=0;q<2;q++) ypf[q] = *(const uint4*)&Yg[(size_t)ar*NN + k0 + ac*8 + q*64];
    }
    __syncthreads();
    const int cb = c&1;
#pragma unroll
    for (int s=0;s<4;s++) {
      bf16x8 af  = *(const bf16x8*)&As[cb][rh*16+m][s*32+quad*8];
      bf16x8 bb0 = *(const bf16x8*)&Ys[cb][ch*16+m][s*32+quad*8];
      acc0 = MFMA16x16(af, bb0, acc0, 0, 0, 0);
    }
    if (c<7) {
      const int nb = (c+1)&1;
#pragma unroll
      for (int q=0;q<2;q++) *(uint4*)&As[nb][ar][ac*8+q*64] = apf[q];
#pragma unroll
      for (int q=0;q<2;q++) *(uint4*)&Ys[nb][ar][ac*8+q*64] = ypf[q];
    }
  }
  __syncthreads();
#pragma unroll
  for (int r=0;r<4;r++) P[rh*16+quad*4+r][ch*16+m] = acc0[r];
  __syncthreads();
  const int row = tid>>3, jr = tid&7, n = i0+row, bn = b*NN+n;
  if (MODE == 0) {          // P1_FIRST: ba=b1r, bb=b1u, cW=g1cW
#pragma unroll
    for (int q=0;q<2;q++) {
      int j = jr*2+q;
      float r1 = sigmf(P[row][j]    + ba[j]);
      float u1 = sigmf(P[row][16+j] + bb[j]);
      g_u1[(size_t)bn*16+j] = u1;
      E1[row][j] = r1 * g_h1[(size_t)bn*16+j];
    }
    __syncthreads();
    const float* xr = xp + ((size_t)b*TT*NN + n)*FF;
    float x0 = xr[0], x1 = xr[1];
#pragma unroll
    for (int q=0;q<2;q++) {
      int j = jr*2+q;
      float s = fmaf(x0, cW[j*18+0], x1*cW[j*18+1]);
#pragma unroll
      for (int f=0;f<16;f++) s = fmaf(E1[row][f], cW[j*18+2+f], s);
      g_cin[((size_t)(b*32+j))*NN + n] = f2bf(s);
    }
  } else if (MODE == 3) {   // P3_LAST: ba=b2r, bb=b2u, cW=g2cW
#pragma unroll
    for (int q=0;q<2;q++) {
      int j = jr*2+q;
      float r2 = sigmf(P[row][j]    + ba[j]);
      float u2 = sigmf(P[row][16+j] + bb[j]);
      g_u2[(size_t)bn*16+j] = u2;
      E1[row][j] = r2 * g_h2[(size_t)bn*16+j];
      E2[row][j] = g_h1[(size_t)bn*16+j];
    }
    __syncthreads();
#pragma unroll
    for (int q=0;q<2;q++) {
      int j = jr*2+q;
      float s = 0.f;
#pragma unroll
      for (int f=0;f<16;f++) s = fmaf(E2[row][f], cW[j*32+f], s);
#pragma unroll
      for (int f=0;f<16;f++) s = fmaf(E1[row][f], cW[j*32+16+f], s);
      g_cin[((size_t)(b*32+j))*NN + n] = f2bf(s);
    }
  } else {                  // KB / KB_TAIL: ba=b2c, bb=b1c
#pragma unroll
    for (int q=0;q<2;q++) {
      int j = jr*2+q;
      float c2v = tanhf(P[row][j] + ba[j]);
      float u2v = g_u2[(size_t)bn*16+j];
      float h2o = g_h2[(size_t)bn*16+j];
      float h2n = u2v*h2o + (1.f-u2v)*c2v;
      g_h2[(size_t)bn*16+j] = h2n;
      E2[row][j] = h2n;
      float c1v = tanhf(P[row][16+j] + bb[j]);
      float u1v = g_u1[(size_t)bn*16+j];
      float h1o = g_h1[(size_t)bn*16+j];
      float h1n = u1v*h1o + (1.f-u1v)*c1v;
      g_h1[(size_t)bn*16+j] = h1n;
      E1[row][j] = h1n;
    }
    __syncthreads();
    float x0 = 0.f, x1 = 0.f;
    if (MODE == 1) {
      const float* xr = xp + ((size_t)b*TT*NN + n)*FF;
      x0 = xr[0]; x1 = xr[1];
    }
#pragma unroll
    for (int q2=0;q2<4;q2++) {
      int j2 = jr*4+q2;
      const float* W2 = (j2<16) ? (w2r + j2*32) : (w2u + (j2-16)*32);
      float s = 0.f;
#pragma unroll
      for (int f=0;f<16;f++) s = fmaf(E1[row][f], W2[f], s);
#pragma unroll
      for (int f=0;f<16;f++) s = fmaf(E2[row][f], W2[16+f], s);
      g_ru[((size_t)(b*64+j2))*NN + n] = f2bf(s);
      if (MODE == 1) {
        const float* W1 = (j2<16) ? (w1r + j2*18) : (w1u + (j2-16)*18);
        float s1 = fmaf(x0, W1[0], x1*W1[1]);
#pragma unroll
        for (int f=0;f<16;f++) s1 = fmaf(E1[row][f], W1[2+f], s1);
        g_ru[((size_t)(b*64+32+j2))*NN + n] = f2bf(s1);
      }
    }
  }
}

// ============ width-16 pass ============
// MODE 0 = P2F (c1(0) -> h1; ru2(0) [h2=0] + ru1(1))
// MODE 1 = P4L (c2(23) -> h2; small_in -> g_ru[j<16])
// MODE 2 = FIN (out = tanh(P[:,0:2]+gcnb))
template<int MODE>
__global__ __launch_bounds__(256)
void k_w16(const float* __restrict__ xp, const float* __restrict__ ba,
           const float* __restrict__ w1r, const float* __restrict__ w1u,
           const float* __restrict__ w2r, const float* __restrict__ w2u,
           const float* __restrict__ gcnW, const float* __restrict__ gcnb,
           float* __restrict__ out) {
  __shared__ u16 As[32][136];
  __shared__ u16 Ys[16][136];
  __shared__ float P2[2][32][17];
  __shared__ float E1[32][17];
  const int b = blockIdx.y, i0 = blockIdx.x*32, tid = threadIdx.x;
  const int w = tid>>6, lane = tid&63, m = lane&15, quad = lane>>4;
  const int rg = w&1, kh = w>>1;
  const int ar = tid>>3, ac = tid&7;
  const int yrr = tid>>4, ycc = tid&15;
  const u16* Ag = g_Ab + ((size_t)(b*NN+i0))*NN;
  const u16* Yg = (MODE==2) ? (g_ru + (size_t)b*64*NN) : (g_cin + (size_t)b*32*NN);
  f32x4 acc0={0,0,0,0};
  for (int k0=0;k0<NN;k0+=128) {
    __syncthreads();
#pragma unroll
    for (int q=0;q<2;q++)
      *(uint4*)&As[ar][ac*8+q*64] = *(const uint4*)&Ag[(size_t)ar*NN + k0 + ac*8 + q*64];
    *(uint4*)&Ys[yrr][ycc*8] = *(const uint4*)&Yg[(size_t)yrr*NN + k0 + ycc*8];
    __syncthreads();
#pragma unroll
    for (int s=0;s<2;s++) {
      int ks = kh*2+s;
      bf16x8 af  = *(const bf16x8*)&As[rg*16+m][ks*32+quad*8];
      bf16x8 bf_ = *(const bf16x8*)&Ys[m][ks*32+quad*8];
      acc0 = MFMA16x16(af, bf_, acc0, 0, 0, 0);
    }
  }
  __syncthreads();
#pragma unroll
  for (int r=0;r<4;r++) P2[kh][rg*16+quad*4+r][m] = acc0[r];
  __syncthreads();
  const int row = tid>>3, jr = tid&7, n = i0+row, bn = b*NN+n;
  if (MODE == 2) {
    if (jr == 0) {
      float p0 = P2[0][row][0] + P2[1][row][0];
      float p1 = P2[0][row][1] + P2[1][row][1];
      float2 o = make_float2(tanhf(p0 + gcnb[0]), tanhf(p1 + gcnb[1]));
      *(float2*)&out[((size_t)b*NN + n)*FF] = o;
    }
    return;
  }
  if (MODE == 0) {          // ba = b1c
#pragma unroll
    for (int q=0;q<2;q++) {
      int j = jr*2+q;
      float p = P2[0][row][j] + P2[1][row][j];
      float c1v = tanhf(p + ba[j]);
      float u1v = g_u1[(size_t)bn*16+j];
      float h1o = g_h1[(size_t)bn*16+j];
      float h1n = u1v*h1o + (1.f-u1v)*c1v;
      g_h1[(size_t)bn*16+j] = h1n;
      E1[row][j] = h1n;
    }
    __syncthreads();
    const float* xr = xp + ((size_t)b*TT*NN + n)*FF;
    float x0 = xr[0], x1 = xr[1];
#pragma unroll
    for (int q2=0;q2<4;q2++) {
      int j2 = jr*4+q2;
      const float* W2 = (j2<16) ? (w2r + j2*32) : (w2u + (j2-16)*32);
      float s = 0.f;
#pragma unroll
      for (int f=0;f<16;f++) s = fmaf(E1[row][f], W2[f], s);   // h2 = 0
      g_ru[((size_t)(b*64+j2))*NN + n] = f2bf(s);
      const float* W1 = (j2<16) ? (w1r + j2*18) : (w1u + (j2-16)*18);
      float s1 = fmaf(x0, W1[0], x1*W1[1]);
#pragma unroll
      for (int f=0;f<16;f++) s1 = fmaf(E1[row][f], W1[2+f], s1);
      g_ru[((size_t)(b*64+32+j2))*NN + n] = f2bf(s1);
    }
  } else {                  // MODE 1: ba = b2c
#pragma unroll
    for (int q=0;q<2;q++) {
      int j = jr*2+q;
      float p = P2[0][row][j] + P2[1][row][j];
      float c2v = tanhf(p + ba[j]);
      float u2v = g_u2[(size_t)bn*16+j];
      float h2o = g_h2[(size_t)bn*16+j];
      float h2n = u2v*h2o + (1.f-u2v)*c2v;
      g_h2[(size_t)bn*16+j] = h2n;
      E1[row][j] = h2n;
    }
    __syncthreads();
#pragma unroll
    for (int q=0;q<2;q++) {
      int j = jr*2+q;
      float s = 0.f;
      if (j < FF) {
        s = g_c2[b*FF+j];
#pragma unroll
        for (int f=0;f<16;f++) s = fmaf(E1[row][f], gcnW[j*80+f], s);
      }
      g_ru[((size_t)(b*64+j))*NN + n] = f2bf(s);
    }
  }
}

extern "C" void kernel_launch(void* const* d_in, const int* in_sizes, int n_in,
                              void* d_out, int out_size, void* d_ws, size_t ws_size,
                              hipStream_t stream) {
  (void)in_sizes; (void)n_in; (void)d_ws; (void)ws_size; (void)out_size;
  const float* recent = (const float*)d_in[0];
  const float* trend  = (const float*)d_in[1];
  const float* A      = (const float*)d_in[2];
  const float* tfeat  = (const float*)d_in[3];
  const float* g1rW = (const float*)d_in[4];  const float* g1rb = (const float*)d_in[5];
  const float* g1uW = (const float*)d_in[6];  const float* g1ub = (const float*)d_in[7];
  const float* g1cW = (const float*)d_in[8];  const float* g1cb = (const float*)d_in[9];
  const float* g2rW = (const float*)d_in[10]; const float* g2rb = (const float*)d_in[11];
  const float* g2uW = (const float*)d_in[12]; const float* g2ub = (const float*)d_in[13];
  const float* g2cW = (const float*)d_in[14]; const float* g2cb = (const float*)d_in[15];
  const float* Wih0 = (const float*)d_in[16]; const float* Whh0 = (const float*)d_in[17];
  const float* bih0 = (const float*)d_in[18]; const float* bhh0 = (const float*)d_in[19];
  const float* Wih1 = (const float*)d_in[20]; const float* Whh1 = (const float*)d_in[21];
  const float* bih1 = (const float*)d_in[22]; const float* bhh1 = (const float*)d_in[23];
  const float* ffW  = (const float*)d_in[24]; const float* ffb  = (const float*)d_in[25];
  const float* gcnW = (const float*)d_in[26]; const float* gcnb = (const float*)d_in[27];
  float* out = (float*)d_out;

  const dim3 G(32, BB);
  k_convert<<<16384, 256, 0, stream>>>(A);
  k_lstm<<<BB, 128, 0, stream>>>(trend, tfeat, Wih0, Whh0, bih0, bhh0,
                                 Wih1, Whh1, bih1, bhh1, ffW, ffb, gcnW);
  k_init<<<(BB*NN)/256, 256, 0, stream>>>(recent, g1rW, g1uW);

  // P1(0): r1,u1(0), c_in1(0)
  k_w32<0><<<G, 256, 0, stream>>>(recent, g1rb, g1ub, g1cW,
                                  nullptr, nullptr, nullptr, nullptr);
  // P2(0): h1(0); ru2(0) + ru1(1)
  k_w16<0><<<G, 256, 0, stream>>>(recent + (size_t)1*NN*FF, g1cb,
                                  g1rW, g1uW, g2rW, g2uW, nullptr, nullptr, nullptr);
  for (int t=0; t<TT-1; t++) {
    // KA(t): [ru2(t) | ru1(t+1)] pass
    k_ka<<<G, 256, 0, stream>>>(recent + (size_t)(t+1)*NN*FF,
                                g2rb, g2ub, g1rb, g1ub, g2cW, g1cW);
    // KB(t): [c2(t) | c1(t+1)] pass
    if (t < TT-2)
      k_w32<1><<<G, 256, 0, stream>>>(recent + (size_t)(t+2)*NN*FF, g2cb, g1cb, nullptr,
                                      g1rW, g1uW, g2rW, g2uW);
    else
      k_w32<2><<<G, 256, 0, stream>>>(nullptr, g2cb, g1cb, nullptr,
                                      g1rW, g1uW, g2rW, g2uW);
  }
  // P3(23): r2,u2(23), c_in2(23)
  k_w32<3><<<G, 256, 0, stream>>>(nullptr, g2rb, g2ub, g2cW,
                                  nullptr, nullptr, nullptr, nullptr);
  // P4(23): h2(23); small_in
  k_w16<1><<<G, 256, 0, stream>>>(nullptr, g2cb, nullptr, nullptr, nullptr, nullptr,
                                  gcnW, nullptr, nullptr);
  // final GCN
  k_w16<2><<<G, 256, 0, stream>>>(nullptr, nullptr, nullptr, nullptr, nullptr, nullptr,
                                  nullptr, gcnb, out);
}